// Round 4
// baseline (128.392 us; speedup 1.0000x reference)
//
#include <hip/hip_runtime.h>

// CategorySpecificMLP: out = relu(x @ W1[cat] + b1[cat]) @ W2[cat] + b2[cat]
// N=8192, C=100, D=128, H=128, O=64, fp32.
//
// R4: weights via wave-uniform global_load_dwordx4 (VMEM pipe, in-order
// vmcnt -> software-pipelinable; R3's s_load died on lgkmcnt(0) full-drains
// since SMEM retires out-of-order). Double-buffered weight VGPRs, prefetch
// distance 1. 1024-thread blocks = 16 waves/CU (4/SIMD) for latency overlap.
// Separate x / h LDS regions (2 barriers total in the hot path).

#define N_TOK 8192
#define C_CAT 100
#define D_IN  128
#define H_MID 128
#define O_OUT 64
#define TPB   64                          // tokens per mlp block
#define MAX_ITEMS (C_CAT + N_TOK / TPB)   // 228

// ws layout (ints):
//   [256]              n_items
//   [272, 272+3*228)   work items (cat, start, cnt)
//   [2048, 2048+N)     token ids grouped by category

#define COMP(v,k) ((k)==0?(v).x:((k)==1?(v).y:((k)==2?(v).z:(v).w)))

__global__ __launch_bounds__(1024) void prologue_kernel(
    const int* __restrict__ cat_ids, int* __restrict__ ws) {
  __shared__ int cnt[C_CAT];
  __shared__ int cur[C_CAT];
  __shared__ int sc[128], sk[128];
  int t = threadIdx.x;
  if (t < C_CAT) cnt[t] = 0;
  __syncthreads();

  int ids[8];
  #pragma unroll
  for (int k = 0; k < 8; ++k) {
    ids[k] = cat_ids[t + (k << 10)];
    atomicAdd(&cnt[ids[k]], 1);
  }
  __syncthreads();

  int v = 0, ck = 0;
  if (t < 128) {
    v  = (t < C_CAT) ? cnt[t] : 0;
    ck = (v + TPB - 1) / TPB;
    sc[t] = v; sk[t] = ck;
  }
  __syncthreads();
  for (int off = 1; off < 128; off <<= 1) {
    int a = 0, b = 0;
    if (t < 128 && t >= off) { a = sc[t - off]; b = sk[t - off]; }
    __syncthreads();
    if (t < 128) { sc[t] += a; sk[t] += b; }
    __syncthreads();
  }
  if (t < C_CAT) {
    int start = sc[t] - v;     // exclusive prefix of counts
    int ibase = sk[t] - ck;    // exclusive prefix of chunk counts
    cur[t] = start;
    int* items = ws + 272;
    for (int k = 0; k < ck; ++k) {
      items[3 * (ibase + k) + 0] = t;
      items[3 * (ibase + k) + 1] = start + k * TPB;
      items[3 * (ibase + k) + 2] = min(TPB, v - k * TPB);
    }
  }
  if (t == 127) ws[256] = sk[127];
  __syncthreads();

  #pragma unroll
  for (int k = 0; k < 8; ++k) {
    int pos = atomicAdd(&cur[ids[k]], 1);
    ws[2048 + pos] = t + (k << 10);
  }
}

__global__ __launch_bounds__(1024, 4) void mlp_kernel(
    const float* __restrict__ x,  const float* __restrict__ W1,
    const float* __restrict__ b1, const float* __restrict__ W2,
    const float* __restrict__ b2, float* __restrict__ out,
    const int* __restrict__ ws) {
  int bid = blockIdx.x;
  if (bid >= ws[256]) return;
  const int* item = ws + 272 + 3 * bid;
  int cat = item[0], start = item[1], cnt = item[2];
  const int* sorted = ws + 2048;

  // stride 132: row r col c -> bank-quad (33r + c/4)%32; lanes 0..31 cover
  // all quads once, lanes 32..63 alias 2-way (free per m136).
  __shared__ float xs_[TPB][132];   // x tile
  __shared__ float hs_[TPB][132];   // h tile (separate -> one fewer barrier)
  __shared__ int   toks[TPB];

  int tid = threadIdx.x;
  if (tid < TPB) toks[tid] = (tid < cnt) ? sorted[start + tid] : sorted[start];
  __syncthreads();

  // ---- stage x[64][128], 2048 float4 over 1024 threads ----
  {
    int f4 = tid & 31, r0 = tid >> 5;   // 32 rows/pass, 2 passes
    #pragma unroll
    for (int p = 0; p < 2; ++p) {
      int r = r0 + (p << 5);
      float4 v = ((const float4*)(x + (size_t)toks[r] * D_IN))[f4];
      *(float4*)&xs_[r][f4 << 2] = v;
    }
  }
  __syncthreads();

  int lane = tid & 63;      // token slot
  int wv   = tid >> 6;      // wave 0..15

  // ---- layer1: wave wv owns H cols [8wv, 8wv+8) ----
  const float* W1c = W1 + (size_t)cat * (D_IN * H_MID) + (wv << 3);
  {
    const float4* bb1 = (const float4*)(b1 + (size_t)cat * H_MID + (wv << 3));
    float4 a0 = bb1[0], a1 = bb1[1];

    // broadcast VMEM loads of rows d..d+3 (2 float4/row) into VGPR buffers
    #define LOADW1(buf, dbase)                                             \
      { _Pragma("unroll") for (int i = 0; i < 4; ++i) {                    \
          const float4* wr = (const float4*)(W1c + (size_t)((dbase)+i) * H_MID); \
          buf[2*i]   = wr[0];                                              \
          buf[2*i+1] = wr[1];                                              \
        } }

    float4 wa[8], wb[8];
    LOADW1(wa, 0);
    #pragma unroll
    for (int d4 = 0; d4 < D_IN; d4 += 8) {
      LOADW1(wb, d4 + 4);                      // prefetch next 4 rows
      {
        float4 xv = *(float4*)&xs_[lane][d4];
        #pragma unroll
        for (int i = 0; i < 4; ++i) {
          float xsc = COMP(xv, i);
          a0.x = fmaf(xsc, wa[2*i].x,   a0.x);
          a0.y = fmaf(xsc, wa[2*i].y,   a0.y);
          a0.z = fmaf(xsc, wa[2*i].z,   a0.z);
          a0.w = fmaf(xsc, wa[2*i].w,   a0.w);
          a1.x = fmaf(xsc, wa[2*i+1].x, a1.x);
          a1.y = fmaf(xsc, wa[2*i+1].y, a1.y);
          a1.z = fmaf(xsc, wa[2*i+1].z, a1.z);
          a1.w = fmaf(xsc, wa[2*i+1].w, a1.w);
        }
      }
      if (d4 + 8 < D_IN) LOADW1(wa, d4 + 8);   // prefetch following 4 rows
      {
        float4 xv = *(float4*)&xs_[lane][d4 + 4];
        #pragma unroll
        for (int i = 0; i < 4; ++i) {
          float xsc = COMP(xv, i);
          a0.x = fmaf(xsc, wb[2*i].x,   a0.x);
          a0.y = fmaf(xsc, wb[2*i].y,   a0.y);
          a0.z = fmaf(xsc, wb[2*i].z,   a0.z);
          a0.w = fmaf(xsc, wb[2*i].w,   a0.w);
          a1.x = fmaf(xsc, wb[2*i+1].x, a1.x);
          a1.y = fmaf(xsc, wb[2*i+1].y, a1.y);
          a1.z = fmaf(xsc, wb[2*i+1].z, a1.z);
          a1.w = fmaf(xsc, wb[2*i+1].w, a1.w);
        }
      }
    }

    float4 h0, h1;
    h0.x = fmaxf(a0.x, 0.f); h0.y = fmaxf(a0.y, 0.f);
    h0.z = fmaxf(a0.z, 0.f); h0.w = fmaxf(a0.w, 0.f);
    h1.x = fmaxf(a1.x, 0.f); h1.y = fmaxf(a1.y, 0.f);
    h1.z = fmaxf(a1.z, 0.f); h1.w = fmaxf(a1.w, 0.f);
    *(float4*)&hs_[lane][(wv << 3) + 0] = h0;
    *(float4*)&hs_[lane][(wv << 3) + 4] = h1;
  }
  __syncthreads();

  // ---- layer2: wave wv owns O cols [4wv, 4wv+4) ----
  {
    const float* W2c = W2 + (size_t)cat * (H_MID * O_OUT) + (wv << 2);
    float4 c = *(const float4*)(b2 + (size_t)cat * O_OUT + (wv << 2));

    #define LOADW2(buf, hbase)                                             \
      { _Pragma("unroll") for (int i = 0; i < 4; ++i)                      \
          buf[i] = *(const float4*)(W2c + (size_t)((hbase)+i) * O_OUT); }

    float4 wa2[4], wb2[4];
    LOADW2(wa2, 0);
    #pragma unroll
    for (int h4 = 0; h4 < H_MID; h4 += 8) {
      LOADW2(wb2, h4 + 4);
      {
        float4 hv = *(float4*)&hs_[lane][h4];
        #pragma unroll
        for (int i = 0; i < 4; ++i) {
          float hsc = COMP(hv, i);
          c.x = fmaf(hsc, wa2[i].x, c.x);
          c.y = fmaf(hsc, wa2[i].y, c.y);
          c.z = fmaf(hsc, wa2[i].z, c.z);
          c.w = fmaf(hsc, wa2[i].w, c.w);
        }
      }
      if (h4 + 8 < H_MID) LOADW2(wa2, h4 + 8);
      {
        float4 hv = *(float4*)&hs_[lane][h4 + 4];
        #pragma unroll
        for (int i = 0; i < 4; ++i) {
          float hsc = COMP(hv, i);
          c.x = fmaf(hsc, wb2[i].x, c.x);
          c.y = fmaf(hsc, wb2[i].y, c.y);
          c.z = fmaf(hsc, wb2[i].z, c.z);
          c.w = fmaf(hsc, wb2[i].w, c.w);
        }
      }
    }

    if (lane < cnt)
      *(float4*)(out + (size_t)toks[lane] * O_OUT + (wv << 2)) = c;
  }
}

extern "C" void kernel_launch(void* const* d_in, const int* in_sizes, int n_in,
                              void* d_out, int out_size, void* d_ws, size_t ws_size,
                              hipStream_t stream) {
  const float* x       = (const float*)d_in[0];
  const int*   cat_ids = (const int*)  d_in[1];
  const float* W1      = (const float*)d_in[2];
  const float* b1      = (const float*)d_in[3];
  const float* W2      = (const float*)d_in[4];
  const float* b2      = (const float*)d_in[5];
  float* out = (float*)d_out;
  int*   ws  = (int*)d_ws;

  prologue_kernel<<<1, 1024, 0, stream>>>(cat_ids, ws);
  mlp_kernel<<<MAX_ITEMS, 1024, 0, stream>>>(x, W1, b1, W2, b2, out, ws);
}

// Round 5
// 89.476 us; speedup vs baseline: 1.4349x; 1.4349x over previous
//
#include <hip/hip_runtime.h>

// CategorySpecificMLP: out = relu(x @ W1[cat] + b1[cat]) @ W2[cat] + b2[cat]
// N=8192, C=100, D=128, H=128, O=64, fp32.
//
// R5: MFMA path. fp32 emulated as bf16 hi/lo split (3 MFMA products, lo*lo
// dropped: rel err ~2^-16). All fragments stored FRAG-MAJOR in LDS (lane L
// reads fragbase + 16*L -> ds_read_b128, conflict-free). 16x16x32 bf16 MFMA:
//   A: m=lane&15, k=(lane>>4)*8+j ; B: n=lane&15, k=(lane>>4)*8+j
//   C/D: col=lane&15, row=(lane>>4)*4+reg        [verified layouts, m89/m91]
// W1 staged in two 32KB K-phases through one buffer (acc carries across
// phases); X-frag region reused for H-frags after layer1. LDS ~64.3KB.

#define N_TOK 8192
#define C_CAT 100
#define D_IN  128
#define H_MID 128
#define O_OUT 64
#define TPB   64
#define MAX_ITEMS (C_CAT + N_TOK / TPB)   // 228

typedef __attribute__((ext_vector_type(8))) short short8;   // 8 bf16
typedef __attribute__((ext_vector_type(4))) float floatx4;  // 4 fp32 acc

__global__ __launch_bounds__(1024) void prologue_kernel(
    const int* __restrict__ cat_ids, int* __restrict__ ws) {
  __shared__ int cnt[C_CAT];
  __shared__ int cur[C_CAT];
  __shared__ int sc[128], sk[128];
  int t = threadIdx.x;
  if (t < C_CAT) cnt[t] = 0;
  __syncthreads();

  int ids[8];
  #pragma unroll
  for (int k = 0; k < 8; ++k) {
    ids[k] = cat_ids[t + (k << 10)];
    atomicAdd(&cnt[ids[k]], 1);
  }
  __syncthreads();

  int v = 0, ck = 0;
  if (t < 128) {
    v  = (t < C_CAT) ? cnt[t] : 0;
    ck = (v + TPB - 1) / TPB;
    sc[t] = v; sk[t] = ck;
  }
  __syncthreads();
  for (int off = 1; off < 128; off <<= 1) {
    int a = 0, b = 0;
    if (t < 128 && t >= off) { a = sc[t - off]; b = sk[t - off]; }
    __syncthreads();
    if (t < 128) { sc[t] += a; sk[t] += b; }
    __syncthreads();
  }
  if (t < C_CAT) {
    int start = sc[t] - v;
    int ibase = sk[t] - ck;
    cur[t] = start;
    int* items = ws + 272;
    for (int k = 0; k < ck; ++k) {
      items[3 * (ibase + k) + 0] = t;
      items[3 * (ibase + k) + 1] = start + k * TPB;
      items[3 * (ibase + k) + 2] = min(TPB, v - k * TPB);
    }
  }
  if (t == 127) ws[256] = sk[127];
  __syncthreads();

  #pragma unroll
  for (int k = 0; k < 8; ++k) {
    int pos = atomicAdd(&cur[ids[k]], 1);
    ws[2048 + pos] = t + (k << 10);
  }
}

// exact split: hi = truncate-to-bf16 (top 16 bits, exact), r = f - hi (exact
// in fp32), lo = RNE-bf16(r). f ~= hi + lo to ~18 mantissa bits.
__device__ __forceinline__ void bf16_split(float f, short& hi, short& lo) {
  unsigned b  = __builtin_bit_cast(unsigned, f);
  unsigned hb = b & 0xFFFF0000u;
  hi = (short)(hb >> 16);
  float r = f - __builtin_bit_cast(float, hb);
  unsigned rb = __builtin_bit_cast(unsigned, r);
  lo = (short)((rb + 0x7FFFu + ((rb >> 16) & 1u)) >> 16);
}

__global__ __launch_bounds__(256) void mlp_kernel(
    const float* __restrict__ x,  const float* __restrict__ W1,
    const float* __restrict__ b1, const float* __restrict__ W2,
    const float* __restrict__ b2, float* __restrict__ out,
    const int* __restrict__ ws) {
  int bid = blockIdx.x;
  if (bid >= ws[256]) return;
  const int* item = ws + 272 + 3 * bid;
  int cat = item[0], start = item[1], cnt = item[2];
  const int* sorted = ws + 2048;

  // frag-major: frag id f occupies short8 slots [f*64, f*64+64), lane L at +L.
  __shared__ __align__(16) short XF[2][8192];  // X frags; reused as H frags
  __shared__ __align__(16) short WF[2][8192];  // W1 phase frags / W2 frags
  __shared__ int toks[TPB];

  int tid  = threadIdx.x;
  int lane = tid & 63;
  int wv   = tid >> 6;            // wave 0..3 (wave-uniform)

  if (tid < TPB) toks[tid] = (tid < cnt) ? sorted[start + tid] : sorted[start];
  __syncthreads();

  // ---- stage X frags: f = ks*4+mt; wave w handles mt=w (slot S=tid+256p) ----
  #pragma unroll
  for (int p = 0; p < 4; ++p) {
    int f = ((tid + (p << 8)) >> 6);         // = 4p + wv
    int L = lane;
    int mt = f & 3, ks = f >> 2;
    int m  = (mt << 4) + (L & 15);
    int k0 = (ks << 5) + ((L >> 4) << 3);
    const float* xr = x + (size_t)toks[m] * D_IN + k0;
    float4 v0 = *(const float4*)(xr);
    float4 v1 = *(const float4*)(xr + 4);
    float xv[8] = {v0.x, v0.y, v0.z, v0.w, v1.x, v1.y, v1.z, v1.w};
    short8 h8, l8;
    #pragma unroll
    for (int j = 0; j < 8; ++j) { short hh, ll; bf16_split(xv[j], hh, ll); h8[j] = hh; l8[j] = ll; }
    ((short8*)XF[0])[(f << 6) + L] = h8;
    ((short8*)XF[1])[(f << 6) + L] = l8;
  }

  // ---- layer1: acc over 2 K-phases (W1 k-rows [64ph, 64ph+64)) ----
  floatx4 acc[4][2];
  #pragma unroll
  for (int mt = 0; mt < 4; ++mt)
    #pragma unroll
    for (int ntl = 0; ntl < 2; ++ntl) acc[mt][ntl] = 0.f;

  for (int ph = 0; ph < 2; ++ph) {
    // stage W1 phase frags: f = ksl*8 + nt (ksl 0..1, nt 0..7)
    #pragma unroll
    for (int p = 0; p < 4; ++p) {
      int f = ((tid + (p << 8)) >> 6);       // 4p + wv
      int L = lane;
      int nt = f & 7, ksl = f >> 3;
      int n  = (nt << 4) + (L & 15);
      int kb = (ph << 6) + (ksl << 5) + ((L >> 4) << 3);
      const float* wsrc = W1 + ((size_t)cat * D_IN + kb) * H_MID + n;
      float wv8[8];
      #pragma unroll
      for (int j = 0; j < 8; ++j) wv8[j] = wsrc[(size_t)j * H_MID];
      short8 h8, l8;
      #pragma unroll
      for (int j = 0; j < 8; ++j) { short hh, ll; bf16_split(wv8[j], hh, ll); h8[j] = hh; l8[j] = ll; }
      ((short8*)WF[0])[(f << 6) + L] = h8;
      ((short8*)WF[1])[(f << 6) + L] = l8;
    }
    __syncthreads();

    #pragma unroll
    for (int ksl = 0; ksl < 2; ++ksl) {
      int ksg = (ph << 1) + ksl;             // global K-step 0..3
      short8 ah[4], al[4];
      #pragma unroll
      for (int mt = 0; mt < 4; ++mt) {
        ah[mt] = ((short8*)XF[0])[(((ksg << 2) + mt) << 6) + lane];
        al[mt] = ((short8*)XF[1])[(((ksg << 2) + mt) << 6) + lane];
      }
      short8 bh[2], bl[2];
      #pragma unroll
      for (int ntl = 0; ntl < 2; ++ntl) {
        int f = (ksl << 3) + (wv << 1) + ntl;
        bh[ntl] = ((short8*)WF[0])[(f << 6) + lane];
        bl[ntl] = ((short8*)WF[1])[(f << 6) + lane];
      }
      #pragma unroll
      for (int mt = 0; mt < 4; ++mt)
        #pragma unroll
        for (int ntl = 0; ntl < 2; ++ntl) {
          acc[mt][ntl] = __builtin_amdgcn_mfma_f32_16x16x32_bf16(ah[mt], bh[ntl], acc[mt][ntl], 0, 0, 0);
          acc[mt][ntl] = __builtin_amdgcn_mfma_f32_16x16x32_bf16(ah[mt], bl[ntl], acc[mt][ntl], 0, 0, 0);
          acc[mt][ntl] = __builtin_amdgcn_mfma_f32_16x16x32_bf16(al[mt], bh[ntl], acc[mt][ntl], 0, 0, 0);
        }
    }
    __syncthreads();   // WF reads done (next phase overwrites) / XF reads done
  }

  // ---- h epilogue: bias+relu, split, write H-frags into XF (frag ks2=wv) ----
  #pragma unroll
  for (int ntl = 0; ntl < 2; ++ntl) {
    int n = (wv << 5) + (ntl << 4) + (lane & 15);
    float b1v = b1[(size_t)cat * H_MID + n];
    #pragma unroll
    for (int mt = 0; mt < 4; ++mt) {
      #pragma unroll
      for (int r = 0; r < 4; ++r) {
        float hfull = fmaxf(acc[mt][ntl][r] + b1v, 0.f);
        short hh, hl; bf16_split(hfull, hh, hl);
        int m  = (mt << 4) + ((lane >> 4) << 2) + r;
        int L2 = (((n >> 3) & 3) << 4) + (m & 15);
        int sa = (((wv << 2) + mt) << 9) + (L2 << 3) + (n & 7);
        XF[0][sa] = hh; XF[1][sa] = hl;
      }
    }
  }

  // ---- stage W2 frags (concurrent with h-writes): f = ks*4 + nt2 ----
  #pragma unroll
  for (int p = 0; p < 4; ++p) {
    int f = ((tid + (p << 8)) >> 6);         // 4p + wv
    int L = lane;
    int nt = f & 3, ks = f >> 2;
    int n  = (nt << 4) + (L & 15);
    int kb = (ks << 5) + ((L >> 4) << 3);
    const float* wsrc = W2 + ((size_t)cat * H_MID + kb) * O_OUT + n;
    float wv8[8];
    #pragma unroll
    for (int j = 0; j < 8; ++j) wv8[j] = wsrc[(size_t)j * O_OUT];
    short8 h8, l8;
    #pragma unroll
    for (int j = 0; j < 8; ++j) { short hh, ll; bf16_split(wv8[j], hh, ll); h8[j] = hh; l8[j] = ll; }
    ((short8*)WF[0])[(f << 6) + L] = h8;
    ((short8*)WF[1])[(f << 6) + L] = l8;
  }
  __syncthreads();

  // ---- layer2: wave wv owns O cols [16wv, 16wv+16) ----
  floatx4 acc2[4];
  #pragma unroll
  for (int mt = 0; mt < 4; ++mt) acc2[mt] = 0.f;

  #pragma unroll
  for (int ks = 0; ks < 4; ++ks) {
    short8 bh = ((short8*)WF[0])[(((ks << 2) + wv) << 6) + lane];
    short8 bl = ((short8*)WF[1])[(((ks << 2) + wv) << 6) + lane];
    #pragma unroll
    for (int mt = 0; mt < 4; ++mt) {
      short8 ah = ((short8*)XF[0])[(((ks << 2) + mt) << 6) + lane];
      short8 al = ((short8*)XF[1])[(((ks << 2) + mt) << 6) + lane];
      acc2[mt] = __builtin_amdgcn_mfma_f32_16x16x32_bf16(ah, bh, acc2[mt], 0, 0, 0);
      acc2[mt] = __builtin_amdgcn_mfma_f32_16x16x32_bf16(ah, bl, acc2[mt], 0, 0, 0);
      acc2[mt] = __builtin_amdgcn_mfma_f32_16x16x32_bf16(al, bh, acc2[mt], 0, 0, 0);
    }
  }

  // ---- store: D row m=(lane>>4)*4+r (+16mt), col n=lane&15 (+16wv) ----
  {
    int n2 = (wv << 4) + (lane & 15);
    float b2v = b2[(size_t)cat * O_OUT + n2];
    #pragma unroll
    for (int mt = 0; mt < 4; ++mt) {
      #pragma unroll
      for (int r = 0; r < 4; ++r) {
        int m = (mt << 4) + ((lane >> 4) << 2) + r;
        if (m < cnt)
          out[(size_t)toks[m] * O_OUT + n2] = acc2[mt][r] + b2v;
      }
    }
  }
}

extern "C" void kernel_launch(void* const* d_in, const int* in_sizes, int n_in,
                              void* d_out, int out_size, void* d_ws, size_t ws_size,
                              hipStream_t stream) {
  const float* x       = (const float*)d_in[0];
  const int*   cat_ids = (const int*)  d_in[1];
  const float* W1      = (const float*)d_in[2];
  const float* b1      = (const float*)d_in[3];
  const float* W2      = (const float*)d_in[4];
  const float* b2      = (const float*)d_in[5];
  float* out = (float*)d_out;
  int*   ws  = (int*)d_ws;

  prologue_kernel<<<1, 1024, 0, stream>>>(cat_ids, ws);
  mlp_kernel<<<MAX_ITEMS, 256, 0, stream>>>(x, W1, b1, W2, b2, out, ws);
}

// Round 6
// 89.444 us; speedup vs baseline: 1.4354x; 1.0004x over previous
//
#include <hip/hip_runtime.h>

// CategorySpecificMLP: out = relu(x @ W1[cat] + b1[cat]) @ W2[cat] + b2[cat]
// N=8192, C=100, D=128, H=128, O=64, fp32.
//
// R6: (a) mlp issues ALL global loads at entry (lane-varying -> stay vector,
// overlap in vmcnt queue; collapses 5 serial ~900cyc cold-load phases to ~2).
// (b) wave->n-tile map {wv, wv+4}: each thread's prefetched W1/W2 registers
// are exactly its lane's MFMA B-operands -> W never touches LDS; only X/H
// frags (shared across waves) stay in LDS. 3 barriers, 32KB LDS.
// (c) prologue parallelized: zero / 32-block histogram / scan+build /
// 32-block scatter (block-local ranks + global cursor atomics).
// MFMA math identical to R5 (verified, absmax 4.9e-4): bf16 hi/lo split,
// 3 products, frag-major LDS, 16x16x32 layouts per m89/m91.

#define N_TOK 8192
#define C_CAT 100
#define D_IN  128
#define H_MID 128
#define O_OUT 64
#define TPB   64
#define MAX_ITEMS (C_CAT + N_TOK / TPB)   // 228

// ws layout (ints):
//   [0,100)    category counts     [128,228) scatter cursors
//   [256]      n_items             [272, 272+3*228) items (cat,start,cnt)
//   [2048, 2048+N) token ids grouped by category

typedef __attribute__((ext_vector_type(8))) short short8;   // 8 bf16
typedef __attribute__((ext_vector_type(4))) float floatx4;  // 4 fp32 acc

__global__ __launch_bounds__(256) void zero_kernel(int* __restrict__ ws) {
  ws[threadIdx.x] = 0;   // zeros counts [0,100) + cursors [128,228) + slack
}

__global__ __launch_bounds__(256) void hist_kernel(
    const int* __restrict__ cat_ids, int* __restrict__ ws) {
  __shared__ int h[C_CAT];
  int t = threadIdx.x;
  if (t < C_CAT) h[t] = 0;
  __syncthreads();
  int g = blockIdx.x * 256 + t;
  atomicAdd(&h[cat_ids[g]], 1);
  __syncthreads();
  if (t < C_CAT && h[t] > 0) atomicAdd(&ws[t], h[t]);
}

__global__ __launch_bounds__(128) void scan_kernel(int* __restrict__ ws) {
  __shared__ int sc[128], sk[128];
  int t = threadIdx.x;
  int v  = (t < C_CAT) ? ws[t] : 0;
  int ck = (v + TPB - 1) / TPB;
  sc[t] = v; sk[t] = ck;
  __syncthreads();
  for (int off = 1; off < 128; off <<= 1) {
    int a = 0, b = 0;
    if (t >= off) { a = sc[t - off]; b = sk[t - off]; }
    __syncthreads();
    sc[t] += a; sk[t] += b;
    __syncthreads();
  }
  if (t < C_CAT) {
    int start = sc[t] - v;
    int ibase = sk[t] - ck;
    ws[128 + t] = start;             // scatter cursor base
    int* items = ws + 272;
    for (int k = 0; k < ck; ++k) {
      items[3 * (ibase + k) + 0] = t;
      items[3 * (ibase + k) + 1] = start + k * TPB;
      items[3 * (ibase + k) + 2] = min(TPB, v - k * TPB);
    }
  }
  if (t == 127) ws[256] = sk[127];
}

__global__ __launch_bounds__(256) void scatter_kernel(
    const int* __restrict__ cat_ids, int* __restrict__ ws) {
  __shared__ int lcnt[C_CAT];
  __shared__ int gbase[C_CAT];
  int t = threadIdx.x;
  if (t < C_CAT) lcnt[t] = 0;
  __syncthreads();
  int g = blockIdx.x * 256 + t;
  int c = cat_ids[g];
  int r = atomicAdd(&lcnt[c], 1);    // block-local rank
  __syncthreads();
  if (t < C_CAT && lcnt[t] > 0) gbase[t] = atomicAdd(&ws[128 + t], lcnt[t]);
  __syncthreads();
  ws[2048 + gbase[c] + r] = g;
}

// exact split: hi = trunc-bf16 (exact), r = f - hi (exact), lo = RNE-bf16(r)
__device__ __forceinline__ void bf16_split(float f, short& hi, short& lo) {
  unsigned b  = __builtin_bit_cast(unsigned, f);
  unsigned hb = b & 0xFFFF0000u;
  hi = (short)(hb >> 16);
  float r = f - __builtin_bit_cast(float, hb);
  unsigned rb = __builtin_bit_cast(unsigned, r);
  lo = (short)((rb + 0x7FFFu + ((rb >> 16) & 1u)) >> 16);
}

__device__ __forceinline__ void split8(const float* v, short8& h8, short8& l8) {
  #pragma unroll
  for (int j = 0; j < 8; ++j) { short hh, ll; bf16_split(v[j], hh, ll); h8[j] = hh; l8[j] = ll; }
}

__global__ __launch_bounds__(256, 1) void mlp_kernel(
    const float* __restrict__ x,  const float* __restrict__ W1,
    const float* __restrict__ b1, const float* __restrict__ W2,
    const float* __restrict__ b2, float* __restrict__ out,
    const int* __restrict__ ws) {
  int bid = blockIdx.x;
  if (bid >= ws[256]) return;
  const int* item = ws + 272 + 3 * bid;
  int cat = item[0], start = item[1], cnt = item[2];
  const int* sorted = ws + 2048;

  // frag-major LDS: frag f at short8 slots [f*64, f*64+64), lane L at +L.
  __shared__ __align__(16) short XF[2][8192];  // X frags -> H frags (32 KB)
  __shared__ int toks[TPB];

  int tid  = threadIdx.x;
  int lane = tid & 63;
  int wv   = tid >> 6;            // wave 0..3

  // ================= issue ALL global loads now (overlap in vmcnt queue) ===
  if (tid < TPB) toks[tid] = sorted[start + min(tid, cnt - 1)];

  // X: this thread stages frag (ks=p, mt=wv); row m = 16wv + (lane&15)
  int mrow = (wv << 4) + (lane & 15);
  int tok  = sorted[start + (mrow < cnt ? mrow : 0)];
  const float* xr = x + (size_t)tok * D_IN + ((lane >> 4) << 3);
  float xq[4][8];
  #pragma unroll
  for (int p = 0; p < 4; ++p) {
    *(float4*)&xq[p][0] = *(const float4*)(xr + (p << 5));
    *(float4*)&xq[p][4] = *(const float4*)(xr + (p << 5) + 4);
  }

  // W1: thread holds B-operands for frag f=4p+wv -> (ksl=p>>1 via f>>3,
  // ntile = wv or wv+4). w1a = k rows [0,64), w1b = [64,128).
  const float* W1c = W1 + (size_t)cat * (D_IN * H_MID);
  float w1a[4][8], w1b[4][8];
  #pragma unroll
  for (int p = 0; p < 4; ++p) {
    int f   = (p << 2) + wv;
    int nt  = f & 7;                       // wv or wv+4
    int ksl = f >> 3;                      // p>>1
    int n   = (nt << 4) + (lane & 15);
    int kb  = (ksl << 5) + ((lane >> 4) << 3);
    #pragma unroll
    for (int j = 0; j < 8; ++j) {
      w1a[p][j] = W1c[(size_t)(kb + j) * H_MID + n];
      w1b[p][j] = W1c[(size_t)(64 + kb + j) * H_MID + n];
    }
  }

  // W2: thread holds B-operands for frag (ks=p, nt=wv)
  const float* W2c = W2 + (size_t)cat * (H_MID * O_OUT);
  float w2r[4][8];
  {
    int n = (wv << 4) + (lane & 15);
    #pragma unroll
    for (int p = 0; p < 4; ++p) {
      int kb = (p << 5) + ((lane >> 4) << 3);
      #pragma unroll
      for (int j = 0; j < 8; ++j)
        w2r[p][j] = W2c[(size_t)(kb + j) * O_OUT + n];
    }
  }

  // biases
  float b1v[2];
  #pragma unroll
  for (int ntl = 0; ntl < 2; ++ntl) {
    int ntile = wv + (ntl << 2);
    b1v[ntl] = b1[(size_t)cat * H_MID + (ntile << 4) + (lane & 15)];
  }
  float b2v = b2[(size_t)cat * O_OUT + (wv << 4) + (lane & 15)];

  // ================= stage X frags into LDS ================================
  #pragma unroll
  for (int p = 0; p < 4; ++p) {
    short8 h8, l8;
    split8(xq[p], h8, l8);
    int f = (p << 2) + wv;                 // (ks=p, mt=wv)
    ((short8*)XF[0])[(f << 6) + lane] = h8;
    ((short8*)XF[1])[(f << 6) + lane] = l8;
  }
  __syncthreads();                         // B1

  // ================= layer1: A from LDS, B from registers ==================
  floatx4 acc[4][2];
  #pragma unroll
  for (int mt = 0; mt < 4; ++mt)
    #pragma unroll
    for (int ntl = 0; ntl < 2; ++ntl) acc[mt][ntl] = 0.f;

  #pragma unroll
  for (int ksg = 0; ksg < 4; ++ksg) {
    short8 ah[4], al[4];
    #pragma unroll
    for (int mt = 0; mt < 4; ++mt) {
      ah[mt] = ((short8*)XF[0])[(((ksg << 2) + mt) << 6) + lane];
      al[mt] = ((short8*)XF[1])[(((ksg << 2) + mt) << 6) + lane];
    }
    short8 bh[2], bl[2];
    #pragma unroll
    for (int ntl = 0; ntl < 2; ++ntl) {
      // register p index: w1a for ksg 0,1 ; w1b for ksg 2,3 ; p = (ksg&1)*2+ntl
      const float* wreg = (ksg < 2) ? w1a[((ksg & 1) << 1) + ntl]
                                    : w1b[((ksg & 1) << 1) + ntl];
      split8(wreg, bh[ntl], bl[ntl]);
    }
    #pragma unroll
    for (int mt = 0; mt < 4; ++mt)
      #pragma unroll
      for (int ntl = 0; ntl < 2; ++ntl) {
        acc[mt][ntl] = __builtin_amdgcn_mfma_f32_16x16x32_bf16(ah[mt], bh[ntl], acc[mt][ntl], 0, 0, 0);
        acc[mt][ntl] = __builtin_amdgcn_mfma_f32_16x16x32_bf16(ah[mt], bl[ntl], acc[mt][ntl], 0, 0, 0);
        acc[mt][ntl] = __builtin_amdgcn_mfma_f32_16x16x32_bf16(al[mt], bh[ntl], acc[mt][ntl], 0, 0, 0);
      }
  }
  __syncthreads();                         // B2: X reads done before H writes

  // ================= h epilogue: bias+relu+split -> H frags in XF ==========
  #pragma unroll
  for (int ntl = 0; ntl < 2; ++ntl) {
    int ntile = wv + (ntl << 2);
    int n = (ntile << 4) + (lane & 15);
    #pragma unroll
    for (int mt = 0; mt < 4; ++mt) {
      #pragma unroll
      for (int r = 0; r < 4; ++r) {
        float hfull = fmaxf(acc[mt][ntl][r] + b1v[ntl], 0.f);
        short hh, hl; bf16_split(hfull, hh, hl);
        int m  = (mt << 4) + ((lane >> 4) << 2) + r;
        int f2 = ((n >> 5) << 2) + mt;               // (ks2 = n/32, mt)
        int L2 = (((n >> 3) & 3) << 4) + (m & 15);
        int sa = (f2 << 9) + (L2 << 3) + (n & 7);
        XF[0][sa] = hh; XF[1][sa] = hl;
      }
    }
  }
  __syncthreads();                         // B3

  // ================= layer2: A (H) from LDS, B from registers ==============
  floatx4 acc2[4];
  #pragma unroll
  for (int mt = 0; mt < 4; ++mt) acc2[mt] = 0.f;

  #pragma unroll
  for (int ks = 0; ks < 4; ++ks) {
    short8 bh, bl;
    split8(w2r[ks], bh, bl);
    #pragma unroll
    for (int mt = 0; mt < 4; ++mt) {
      short8 ah = ((short8*)XF[0])[(((ks << 2) + mt) << 6) + lane];
      short8 al = ((short8*)XF[1])[(((ks << 2) + mt) << 6) + lane];
      acc2[mt] = __builtin_amdgcn_mfma_f32_16x16x32_bf16(ah, bh, acc2[mt], 0, 0, 0);
      acc2[mt] = __builtin_amdgcn_mfma_f32_16x16x32_bf16(ah, bl, acc2[mt], 0, 0, 0);
      acc2[mt] = __builtin_amdgcn_mfma_f32_16x16x32_bf16(al, bh, acc2[mt], 0, 0, 0);
    }
  }

  // ================= store: row m=(lane>>4)*4+r+16mt, col n=lane&15+16wv ===
  {
    int n2 = (wv << 4) + (lane & 15);
    #pragma unroll
    for (int mt = 0; mt < 4; ++mt) {
      #pragma unroll
      for (int r = 0; r < 4; ++r) {
        int m = (mt << 4) + ((lane >> 4) << 2) + r;
        if (m < cnt)
          out[(size_t)toks[m] * O_OUT + n2] = acc2[mt][r] + b2v;
      }
    }
  }
}

extern "C" void kernel_launch(void* const* d_in, const int* in_sizes, int n_in,
                              void* d_out, int out_size, void* d_ws, size_t ws_size,
                              hipStream_t stream) {
  const float* x       = (const float*)d_in[0];
  const int*   cat_ids = (const int*)  d_in[1];
  const float* W1      = (const float*)d_in[2];
  const float* b1      = (const float*)d_in[3];
  const float* W2      = (const float*)d_in[4];
  const float* b2      = (const float*)d_in[5];
  float* out = (float*)d_out;
  int*   ws  = (int*)d_ws;

  zero_kernel   <<<1,            256, 0, stream>>>(ws);
  hist_kernel   <<<N_TOK / 256,  256, 0, stream>>>(cat_ids, ws);
  scan_kernel   <<<1,            128, 0, stream>>>(ws);
  scatter_kernel<<<N_TOK / 256,  256, 0, stream>>>(cat_ids, ws);
  mlp_kernel    <<<MAX_ITEMS,    256, 0, stream>>>(x, W1, b1, W2, b2, out, ws);
}

// Round 7
// 81.802 us; speedup vs baseline: 1.5695x; 1.0934x over previous
//
#include <hip/hip_runtime.h>

// CategorySpecificMLP: out = relu(x @ W1[cat] + b1[cat]) @ W2[cat] + b2[cat]
// N=8192, C=100, D=128, H=128, O=64, fp32.
//
// R7: SINGLE kernel. Block b -> (cat = b/2, chunk parity = b&1). W1/W2/bias
// loads issue at entry (addresses depend only on blockIdx). Each block
// re-derives its token chunk by scanning cat_ids directly (strided int4
// ownership -> per-thread match counts -> 256-entry LDS prefix scan ->
// rank-windowed scatter into toks[]). The ~2us scan structurally hides the
// W-load latency. chunk+=2 loop is overflow-safe for any count distribution.
// MFMA math identical to R5/R6 (verified absmax 4.9e-4): bf16 hi/lo split,
// 3 products (lo*lo dropped), frag-major LDS, 16x16x32 layouts (m89/m91).

#define N_TOK 8192
#define C_CAT 100
#define D_IN  128
#define H_MID 128
#define O_OUT 64
#define NCHUNK 2
#define GRID (C_CAT * NCHUNK)   // 200 blocks <= 256 CUs: one round

typedef __attribute__((ext_vector_type(8))) short short8;   // 8 bf16
typedef __attribute__((ext_vector_type(4))) float floatx4;  // 4 fp32 acc

// exact split: hi = trunc-bf16 (exact), r = f - hi (exact), lo = RNE-bf16(r)
__device__ __forceinline__ void bf16_split(float f, short& hi, short& lo) {
  unsigned b  = __builtin_bit_cast(unsigned, f);
  unsigned hb = b & 0xFFFF0000u;
  hi = (short)(hb >> 16);
  float r = f - __builtin_bit_cast(float, hb);
  unsigned rb = __builtin_bit_cast(unsigned, r);
  lo = (short)((rb + 0x7FFFu + ((rb >> 16) & 1u)) >> 16);
}

__device__ __forceinline__ void split8(const float* v, short8& h8, short8& l8) {
  #pragma unroll
  for (int j = 0; j < 8; ++j) { short hh, ll; bf16_split(v[j], hh, ll); h8[j] = hh; l8[j] = ll; }
}

__global__ __launch_bounds__(256, 1) void mlp_kernel(
    const float* __restrict__ x,  const int* __restrict__ cat_ids,
    const float* __restrict__ W1, const float* __restrict__ b1,
    const float* __restrict__ W2, const float* __restrict__ b2,
    float* __restrict__ out) {
  int bid  = blockIdx.x;
  int cat  = bid >> 1;
  int j0   = bid & 1;
  int tid  = threadIdx.x;
  int lane = tid & 63;
  int wv   = tid >> 6;            // wave 0..3

  // frag-major LDS: frag f at short8 slots [f*64, f*64+64), lane L at +L.
  __shared__ __align__(16) short XF[2][8192];  // X frags -> H frags (32 KB)
  __shared__ int toks[64];
  __shared__ int sc[256];

  // ======== issue W/bias loads NOW (pure function of blockIdx) =============
  // W1: B-operands for frag f=4p+wv (nt = f&7 in {wv,wv+4}, ksl = f>>3).
  const float* W1c = W1 + (size_t)cat * (D_IN * H_MID);
  float w1a[4][8], w1b[4][8];
  #pragma unroll
  for (int p = 0; p < 4; ++p) {
    int f   = (p << 2) + wv;
    int nt  = f & 7;
    int ksl = f >> 3;
    int n   = (nt << 4) + (lane & 15);
    int kb  = (ksl << 5) + ((lane >> 4) << 3);
    #pragma unroll
    for (int j = 0; j < 8; ++j) {
      w1a[p][j] = W1c[(size_t)(kb + j) * H_MID + n];
      w1b[p][j] = W1c[(size_t)(64 + kb + j) * H_MID + n];
    }
  }
  // W2: B-operands for frag (ks=p, nt=wv)
  const float* W2c = W2 + (size_t)cat * (H_MID * O_OUT);
  float w2r[4][8];
  {
    int n = (wv << 4) + (lane & 15);
    #pragma unroll
    for (int p = 0; p < 4; ++p) {
      int kb = (p << 5) + ((lane >> 4) << 3);
      #pragma unroll
      for (int j = 0; j < 8; ++j)
        w2r[p][j] = W2c[(size_t)(kb + j) * O_OUT + n];
    }
  }
  float b1v[2];
  #pragma unroll
  for (int ntl = 0; ntl < 2; ++ntl)
    b1v[ntl] = b1[(size_t)cat * H_MID + ((wv + (ntl << 2)) << 4) + (lane & 15)];
  float b2v = b2[(size_t)cat * O_OUT + (wv << 4) + (lane & 15)];

  // ======== scan cat_ids: thread owns int4 groups {tid+256k} ===============
  const int4* cid4 = (const int4*)cat_ids;
  int mycnt = 0;
  #pragma unroll
  for (int k = 0; k < 8; ++k) {
    int4 v = cid4[tid + (k << 8)];     // coalesced; 2048 int4 total
    mycnt += (v.x == cat) + (v.y == cat) + (v.z == cat) + (v.w == cat);
  }
  sc[tid] = mycnt;
  __syncthreads();
  for (int off = 1; off < 256; off <<= 1) {
    int a = (tid >= off) ? sc[tid - off] : 0;
    __syncthreads();
    sc[tid] += a;
    __syncthreads();
  }
  int TOT   = sc[255];                 // tokens in this category
  int ebase = sc[tid] - mycnt;         // this thread's first rank

  // ======== per-chunk MLP ==================================================
  for (int chunk = j0; (chunk << 6) < TOT; chunk += NCHUNK) {
    int ccnt = min(64, TOT - (chunk << 6));
    __syncthreads();                   // prev-iter toks/XF readers done
    if (tid < 64) toks[tid] = 0;       // padded rows -> token 0 (not stored)
    __syncthreads();
    {                                  // scatter my matches in rank window
      int r = ebase, lo = chunk << 6;
      #pragma unroll
      for (int k = 0; k < 8; ++k) {
        int4 v = cid4[tid + (k << 8)]; // L1/L2-hot re-read
        int p = (tid + (k << 8)) << 2;
        if (v.x == cat) { int rel = r - lo; if ((unsigned)rel < 64u) toks[rel] = p;     ++r; }
        if (v.y == cat) { int rel = r - lo; if ((unsigned)rel < 64u) toks[rel] = p + 1; ++r; }
        if (v.z == cat) { int rel = r - lo; if ((unsigned)rel < 64u) toks[rel] = p + 2; ++r; }
        if (v.w == cat) { int rel = r - lo; if ((unsigned)rel < 64u) toks[rel] = p + 3; ++r; }
      }
    }
    __syncthreads();

    // ---- X loads + stage frags (ks=p, mt=wv) ----
    int mrow = (wv << 4) + (lane & 15);
    int tok  = toks[mrow];
    const float* xr = x + (size_t)tok * D_IN + ((lane >> 4) << 3);
    float xq[4][8];
    #pragma unroll
    for (int p = 0; p < 4; ++p) {
      *(float4*)&xq[p][0] = *(const float4*)(xr + (p << 5));
      *(float4*)&xq[p][4] = *(const float4*)(xr + (p << 5) + 4);
    }
    #pragma unroll
    for (int p = 0; p < 4; ++p) {
      short8 h8, l8;
      split8(xq[p], h8, l8);
      int f = (p << 2) + wv;
      ((short8*)XF[0])[(f << 6) + lane] = h8;
      ((short8*)XF[1])[(f << 6) + lane] = l8;
    }
    __syncthreads();                   // B1

    // ---- layer1: A from LDS, B from registers ----
    floatx4 acc[4][2];
    #pragma unroll
    for (int mt = 0; mt < 4; ++mt)
      #pragma unroll
      for (int ntl = 0; ntl < 2; ++ntl) acc[mt][ntl] = 0.f;

    #pragma unroll
    for (int ksg = 0; ksg < 4; ++ksg) {
      short8 ah[4], al[4];
      #pragma unroll
      for (int mt = 0; mt < 4; ++mt) {
        ah[mt] = ((short8*)XF[0])[(((ksg << 2) + mt) << 6) + lane];
        al[mt] = ((short8*)XF[1])[(((ksg << 2) + mt) << 6) + lane];
      }
      short8 bh[2], bl[2];
      #pragma unroll
      for (int ntl = 0; ntl < 2; ++ntl) {
        const float* wreg = (ksg < 2) ? w1a[((ksg & 1) << 1) + ntl]
                                      : w1b[((ksg & 1) << 1) + ntl];
        split8(wreg, bh[ntl], bl[ntl]);
      }
      #pragma unroll
      for (int mt = 0; mt < 4; ++mt)
        #pragma unroll
        for (int ntl = 0; ntl < 2; ++ntl) {
          acc[mt][ntl] = __builtin_amdgcn_mfma_f32_16x16x32_bf16(ah[mt], bh[ntl], acc[mt][ntl], 0, 0, 0);
          acc[mt][ntl] = __builtin_amdgcn_mfma_f32_16x16x32_bf16(ah[mt], bl[ntl], acc[mt][ntl], 0, 0, 0);
          acc[mt][ntl] = __builtin_amdgcn_mfma_f32_16x16x32_bf16(al[mt], bh[ntl], acc[mt][ntl], 0, 0, 0);
        }
    }
    __syncthreads();                   // B2: X reads done before H writes

    // ---- h epilogue: bias+relu+split -> H frags in XF ----
    #pragma unroll
    for (int ntl = 0; ntl < 2; ++ntl) {
      int ntile = wv + (ntl << 2);
      int n = (ntile << 4) + (lane & 15);
      #pragma unroll
      for (int mt = 0; mt < 4; ++mt) {
        #pragma unroll
        for (int r = 0; r < 4; ++r) {
          float hfull = fmaxf(acc[mt][ntl][r] + b1v[ntl], 0.f);
          short hh, hl; bf16_split(hfull, hh, hl);
          int m  = (mt << 4) + ((lane >> 4) << 2) + r;
          int f2 = ((n >> 5) << 2) + mt;             // (ks2 = n/32, mt)
          int L2 = (((n >> 3) & 3) << 4) + (m & 15);
          int sa = (f2 << 9) + (L2 << 3) + (n & 7);
          XF[0][sa] = hh; XF[1][sa] = hl;
        }
      }
    }
    __syncthreads();                   // B3

    // ---- layer2: A (H) from LDS, B from registers ----
    floatx4 acc2[4];
    #pragma unroll
    for (int mt = 0; mt < 4; ++mt) acc2[mt] = 0.f;

    #pragma unroll
    for (int ks = 0; ks < 4; ++ks) {
      short8 bh, bl;
      split8(w2r[ks], bh, bl);
      #pragma unroll
      for (int mt = 0; mt < 4; ++mt) {
        short8 ah = ((short8*)XF[0])[(((ks << 2) + mt) << 6) + lane];
        short8 al = ((short8*)XF[1])[(((ks << 2) + mt) << 6) + lane];
        acc2[mt] = __builtin_amdgcn_mfma_f32_16x16x32_bf16(ah, bh, acc2[mt], 0, 0, 0);
        acc2[mt] = __builtin_amdgcn_mfma_f32_16x16x32_bf16(ah, bl, acc2[mt], 0, 0, 0);
        acc2[mt] = __builtin_amdgcn_mfma_f32_16x16x32_bf16(al, bh, acc2[mt], 0, 0, 0);
      }
    }

    // ---- store: row m=(lane>>4)*4+r+16mt, col n=lane&15+16wv ----
    {
      int n2 = (wv << 4) + (lane & 15);
      #pragma unroll
      for (int mt = 0; mt < 4; ++mt) {
        #pragma unroll
        for (int r = 0; r < 4; ++r) {
          int m = (mt << 4) + ((lane >> 4) << 2) + r;
          if (m < ccnt)
            out[(size_t)toks[m] * O_OUT + n2] = acc2[mt][r] + b2v;
        }
      }
    }
  }
}

extern "C" void kernel_launch(void* const* d_in, const int* in_sizes, int n_in,
                              void* d_out, int out_size, void* d_ws, size_t ws_size,
                              hipStream_t stream) {
  const float* x       = (const float*)d_in[0];
  const int*   cat_ids = (const int*)  d_in[1];
  const float* W1      = (const float*)d_in[2];
  const float* b1      = (const float*)d_in[3];
  const float* W2      = (const float*)d_in[4];
  const float* b2      = (const float*)d_in[5];
  float* out = (float*)d_out;

  mlp_kernel<<<GRID, 256, 0, stream>>>(x, cat_ids, W1, b1, W2, b2, out);
}

// Round 8
// 81.510 us; speedup vs baseline: 1.5752x; 1.0036x over previous
//
#include <hip/hip_runtime.h>

// CategorySpecificMLP: out = relu(x @ W1[cat] + b1[cat]) @ W2[cat] + b2[cat]
// N=8192, C=100, D=128, H=128, O=64, fp32.
//
// R8 (on R7's single-kernel design): shorten the serial critical path.
//  - cat_ids loads issue FIRST (count waits on 8 loads, not 104);
//    W-register loads issue after, their latency shadowed by scan/scatter.
//  - 256-entry Hillis-Steele (16 barriers) -> __shfl_up wave scan + 1 barrier
//    (order stays tid-major/k-ascending: both parity blocks agree).
//  - toks[] zero-init dropped (clamped at use): 6 -> 5 barriers per chunk.
// MFMA math identical to R5-R7 (verified absmax 4.9e-4): bf16 hi/lo split,
// 3 products (lo*lo dropped), frag-major LDS, 16x16x32 layouts (m89/m91).

#define N_TOK 8192
#define C_CAT 100
#define D_IN  128
#define H_MID 128
#define O_OUT 64
#define NCHUNK 2
#define GRID (C_CAT * NCHUNK)   // 200 blocks <= 256 CUs: one round

typedef __attribute__((ext_vector_type(8))) short short8;   // 8 bf16
typedef __attribute__((ext_vector_type(4))) float floatx4;  // 4 fp32 acc

// exact split: hi = trunc-bf16 (exact), r = f - hi (exact), lo = RNE-bf16(r)
__device__ __forceinline__ void bf16_split(float f, short& hi, short& lo) {
  unsigned b  = __builtin_bit_cast(unsigned, f);
  unsigned hb = b & 0xFFFF0000u;
  hi = (short)(hb >> 16);
  float r = f - __builtin_bit_cast(float, hb);
  unsigned rb = __builtin_bit_cast(unsigned, r);
  lo = (short)((rb + 0x7FFFu + ((rb >> 16) & 1u)) >> 16);
}

__device__ __forceinline__ void split8(const float* v, short8& h8, short8& l8) {
  #pragma unroll
  for (int j = 0; j < 8; ++j) { short hh, ll; bf16_split(v[j], hh, ll); h8[j] = hh; l8[j] = ll; }
}

__global__ __launch_bounds__(256, 1) void mlp_kernel(
    const float* __restrict__ x,  const int* __restrict__ cat_ids,
    const float* __restrict__ W1, const float* __restrict__ b1,
    const float* __restrict__ W2, const float* __restrict__ b2,
    float* __restrict__ out) {
  int bid  = blockIdx.x;
  int cat  = bid >> 1;
  int j0   = bid & 1;
  int tid  = threadIdx.x;
  int lane = tid & 63;
  int wv   = tid >> 6;            // wave 0..3

  // frag-major LDS: frag f at short8 slots [f*64, f*64+64), lane L at +L.
  __shared__ __align__(16) short XF[2][8192];  // X frags -> H frags (32 KB)
  __shared__ int toks[64];
  __shared__ int wsum[4];

  // ======== 1) cat_ids loads FIRST: count only waits on these 8 ===========
  const int4* cid4 = (const int4*)cat_ids;
  int4 cv[8];
  #pragma unroll
  for (int k = 0; k < 8; ++k) cv[k] = cid4[tid + (k << 8)];   // coalesced

  int mycnt = 0;
  #pragma unroll
  for (int k = 0; k < 8; ++k)
    mycnt += (cv[k].x == cat) + (cv[k].y == cat) + (cv[k].z == cat) + (cv[k].w == cat);

  // ======== 2) W/bias loads issue now; latency shadowed by scan/scatter ====
  const float* W1c = W1 + (size_t)cat * (D_IN * H_MID);
  float w1a[4][8], w1b[4][8];
  #pragma unroll
  for (int p = 0; p < 4; ++p) {
    int f   = (p << 2) + wv;
    int nt  = f & 7;                       // wv or wv+4
    int ksl = f >> 3;
    int n   = (nt << 4) + (lane & 15);
    int kb  = (ksl << 5) + ((lane >> 4) << 3);
    #pragma unroll
    for (int j = 0; j < 8; ++j) {
      w1a[p][j] = W1c[(size_t)(kb + j) * H_MID + n];
      w1b[p][j] = W1c[(size_t)(64 + kb + j) * H_MID + n];
    }
  }
  const float* W2c = W2 + (size_t)cat * (H_MID * O_OUT);
  float w2r[4][8];
  {
    int n = (wv << 4) + (lane & 15);
    #pragma unroll
    for (int p = 0; p < 4; ++p) {
      int kb = (p << 5) + ((lane >> 4) << 3);
      #pragma unroll
      for (int j = 0; j < 8; ++j)
        w2r[p][j] = W2c[(size_t)(kb + j) * O_OUT + n];
    }
  }
  float b1v[2];
  #pragma unroll
  for (int ntl = 0; ntl < 2; ++ntl)
    b1v[ntl] = b1[(size_t)cat * H_MID + ((wv + (ntl << 2)) << 4) + (lane & 15)];
  float b2v = b2[(size_t)cat * O_OUT + (wv << 4) + (lane & 15)];

  // ======== 3) shfl wave-scan + single barrier =============================
  int s = mycnt;                           // inclusive scan within wave
  #pragma unroll
  for (int off = 1; off < 64; off <<= 1) {
    int u = __shfl_up(s, off, 64);
    if (lane >= off) s += u;
  }
  if (lane == 63) wsum[wv] = s;
  __syncthreads();
  int base = 0;
  #pragma unroll
  for (int w = 0; w < 4; ++w) base += (w < wv) ? wsum[w] : 0;
  int ebase = base + s - mycnt;            // exclusive global rank (tid-major)
  int TOT   = wsum[0] + wsum[1] + wsum[2] + wsum[3];

  // ======== per-chunk MLP ==================================================
  for (int chunk = j0; (chunk << 6) < TOT; chunk += NCHUNK) {
    int ccnt = min(64, TOT - (chunk << 6));
    __syncthreads();                       // A: prev-iter toks readers done
    {                                      // scatter my matches in rank window
      int r = ebase, lo = chunk << 6;
      #pragma unroll
      for (int k = 0; k < 8; ++k) {
        int4 v = cv[k];
        int p = (tid + (k << 8)) << 2;
        if (v.x == cat) { int rel = r - lo; if ((unsigned)rel < 64u) toks[rel] = p;     ++r; }
        if (v.y == cat) { int rel = r - lo; if ((unsigned)rel < 64u) toks[rel] = p + 1; ++r; }
        if (v.z == cat) { int rel = r - lo; if ((unsigned)rel < 64u) toks[rel] = p + 2; ++r; }
        if (v.w == cat) { int rel = r - lo; if ((unsigned)rel < 64u) toks[rel] = p + 3; ++r; }
      }
    }
    __syncthreads();                       // B: toks visible

    // ---- X gather + stage frags (ks=p, mt=wv) ----
    int mrow = (wv << 4) + (lane & 15);
    int tok  = (mrow < ccnt) ? toks[mrow] : 0;   // clamp: padded rows read row 0
    const float* xr = x + (size_t)tok * D_IN + ((lane >> 4) << 3);
    float xq[4][8];
    #pragma unroll
    for (int p = 0; p < 4; ++p) {
      *(float4*)&xq[p][0] = *(const float4*)(xr + (p << 5));
      *(float4*)&xq[p][4] = *(const float4*)(xr + (p << 5) + 4);
    }
    #pragma unroll
    for (int p = 0; p < 4; ++p) {
      short8 h8, l8;
      split8(xq[p], h8, l8);
      int f = (p << 2) + wv;
      ((short8*)XF[0])[(f << 6) + lane] = h8;
      ((short8*)XF[1])[(f << 6) + lane] = l8;
    }
    __syncthreads();                       // C: XF visible

    // ---- layer1: A from LDS, B from registers ----
    floatx4 acc[4][2];
    #pragma unroll
    for (int mt = 0; mt < 4; ++mt)
      #pragma unroll
      for (int ntl = 0; ntl < 2; ++ntl) acc[mt][ntl] = 0.f;

    #pragma unroll
    for (int ksg = 0; ksg < 4; ++ksg) {
      short8 ah[4], al[4];
      #pragma unroll
      for (int mt = 0; mt < 4; ++mt) {
        ah[mt] = ((short8*)XF[0])[(((ksg << 2) + mt) << 6) + lane];
        al[mt] = ((short8*)XF[1])[(((ksg << 2) + mt) << 6) + lane];
      }
      short8 bh[2], bl[2];
      #pragma unroll
      for (int ntl = 0; ntl < 2; ++ntl) {
        const float* wreg = (ksg < 2) ? w1a[((ksg & 1) << 1) + ntl]
                                      : w1b[((ksg & 1) << 1) + ntl];
        split8(wreg, bh[ntl], bl[ntl]);
      }
      #pragma unroll
      for (int mt = 0; mt < 4; ++mt)
        #pragma unroll
        for (int ntl = 0; ntl < 2; ++ntl) {
          acc[mt][ntl] = __builtin_amdgcn_mfma_f32_16x16x32_bf16(ah[mt], bh[ntl], acc[mt][ntl], 0, 0, 0);
          acc[mt][ntl] = __builtin_amdgcn_mfma_f32_16x16x32_bf16(ah[mt], bl[ntl], acc[mt][ntl], 0, 0, 0);
          acc[mt][ntl] = __builtin_amdgcn_mfma_f32_16x16x32_bf16(al[mt], bh[ntl], acc[mt][ntl], 0, 0, 0);
        }
    }
    __syncthreads();                       // D: XF reads done before H writes

    // ---- h epilogue: bias+relu+split -> H frags in XF ----
    #pragma unroll
    for (int ntl = 0; ntl < 2; ++ntl) {
      int ntile = wv + (ntl << 2);
      int n = (ntile << 4) + (lane & 15);
      #pragma unroll
      for (int mt = 0; mt < 4; ++mt) {
        #pragma unroll
        for (int r = 0; r < 4; ++r) {
          float hfull = fmaxf(acc[mt][ntl][r] + b1v[ntl], 0.f);
          short hh, hl; bf16_split(hfull, hh, hl);
          int m  = (mt << 4) + ((lane >> 4) << 2) + r;
          int f2 = ((n >> 5) << 2) + mt;             // (ks2 = n/32, mt)
          int L2 = (((n >> 3) & 3) << 4) + (m & 15);
          int sa = (f2 << 9) + (L2 << 3) + (n & 7);
          XF[0][sa] = hh; XF[1][sa] = hl;
        }
      }
    }
    __syncthreads();                       // E: H visible

    // ---- layer2: A (H) from LDS, B from registers ----
    floatx4 acc2[4];
    #pragma unroll
    for (int mt = 0; mt < 4; ++mt) acc2[mt] = 0.f;

    #pragma unroll
    for (int ks = 0; ks < 4; ++ks) {
      short8 bh, bl;
      split8(w2r[ks], bh, bl);
      #pragma unroll
      for (int mt = 0; mt < 4; ++mt) {
        short8 ah = ((short8*)XF[0])[(((ks << 2) + mt) << 6) + lane];
        short8 al = ((short8*)XF[1])[(((ks << 2) + mt) << 6) + lane];
        acc2[mt] = __builtin_amdgcn_mfma_f32_16x16x32_bf16(ah, bh, acc2[mt], 0, 0, 0);
        acc2[mt] = __builtin_amdgcn_mfma_f32_16x16x32_bf16(ah, bl, acc2[mt], 0, 0, 0);
        acc2[mt] = __builtin_amdgcn_mfma_f32_16x16x32_bf16(al, bh, acc2[mt], 0, 0, 0);
      }
    }

    // ---- store: row m=(lane>>4)*4+r+16mt, col n=lane&15+16wv ----
    {
      int n2 = (wv << 4) + (lane & 15);
      #pragma unroll
      for (int mt = 0; mt < 4; ++mt) {
        #pragma unroll
        for (int r = 0; r < 4; ++r) {
          int m = (mt << 4) + ((lane >> 4) << 2) + r;
          if (m < ccnt)
            out[(size_t)toks[m] * O_OUT + n2] = acc2[mt][r] + b2v;
        }
      }
    }
  }
}

extern "C" void kernel_launch(void* const* d_in, const int* in_sizes, int n_in,
                              void* d_out, int out_size, void* d_ws, size_t ws_size,
                              hipStream_t stream) {
  const float* x       = (const float*)d_in[0];
  const int*   cat_ids = (const int*)  d_in[1];
  const float* W1      = (const float*)d_in[2];
  const float* b1      = (const float*)d_in[3];
  const float* W2      = (const float*)d_in[4];
  const float* b2      = (const float*)d_in[5];
  float* out = (float*)d_out;

  mlp_kernel<<<GRID, 256, 0, stream>>>(x, cat_ids, W1, b1, W2, b2, out);
}